// Round 2
// baseline (429.916 us; speedup 1.0000x reference)
//
#include <hip/hip_runtime.h>
#include <math.h>

#define K_DIM 8192
#define M_DIM 8192
#define N_DIM 8
#define RED_BLOCKS 2048   // pass-1 blocks; each covers a contiguous 128 KiB of W

// ---------------------------------------------------------------------------
// Pass 1: per-block partial sums of |W| (contiguous 128 KiB slice per block,
// compile-time 32-iteration loop for load pipelining). Blocks 0..255 also do
// the activation per-64-group quantization (independent work, fused here).
//   x_hat = rint(x/a_scale)*a_scale, a_scale = max(max|xg|/127, 1e-8)
// ---------------------------------------------------------------------------
__global__ __launch_bounds__(256) void k_pass1(const float4* __restrict__ W4,
                                               const float* __restrict__ x,
                                               double* __restrict__ partials,
                                               float* __restrict__ xh) {
    const float4* p = W4 + (size_t)blockIdx.x * 8192 + threadIdx.x;
    float s0 = 0.f, s1 = 0.f, s2 = 0.f, s3 = 0.f;
    #pragma unroll 8
    for (int j = 0; j < 32; ++j) {
        float4 v = p[(size_t)j * 256];
        s0 += fabsf(v.x); s1 += fabsf(v.y);
        s2 += fabsf(v.z); s3 += fabsf(v.w);
    }
    float s = (s0 + s1) + (s2 + s3);
    #pragma unroll
    for (int off = 32; off > 0; off >>= 1) s += __shfl_xor(s, off, 64);
    __shared__ float sm[4];
    if ((threadIdx.x & 63) == 0) sm[threadIdx.x >> 6] = s;
    __syncthreads();
    if (threadIdx.x == 0) {
        double t = ((double)sm[0] + (double)sm[1]) +
                   ((double)sm[2] + (double)sm[3]);
        partials[blockIdx.x] = t;
    }

    // fused activation quantization: 256 blocks x 256 threads == N*K = 65536
    if (blockIdx.x < (N_DIM * K_DIM) / 256) {
        int idx = blockIdx.x * 256 + threadIdx.x;
        float v = x[idx];
        float a = fabsf(v);
        #pragma unroll
        for (int off = 32; off > 0; off >>= 1)
            a = fmaxf(a, __shfl_xor(a, off, 64));
        float scale = fmaxf(a / 127.0f, 1e-8f);
        xh[idx] = rintf(v / scale) * scale;
    }
}

// ---------------------------------------------------------------------------
// Pass 2: every block deterministically reduces the 2048 partials (identical
// bit-for-bit in all blocks), derives s_w / w_deq, then streams its 16 rows
// of W with on-the-fly ternary quantization. x_hat (256 KiB) is read straight
// from global — it is L2-resident on every XCD, so no LDS, no barriers in
// the K loop, and the compiler can pipeline the W loads across iterations.
// ---------------------------------------------------------------------------
__device__ __forceinline__ float quant1(float w, float s_w) {
    // reference: clip(round(w*s_w), -1, 1); rintf == half-even == np.round
    return fminf(1.0f, fmaxf(-1.0f, rintf(w * s_w)));
}

__global__ __launch_bounds__(256) void k_pass2(const float* __restrict__ W,
                                               const float* __restrict__ xh,
                                               const double* __restrict__ partials,
                                               float* __restrict__ out) {
    // --- replicated deterministic scalar reduce (same order in every block) ---
    double s = 0.0;
    #pragma unroll
    for (int j = 0; j < RED_BLOCKS / 256; ++j)
        s += partials[threadIdx.x + j * 256];
    #pragma unroll
    for (int off = 32; off > 0; off >>= 1) s += __shfl_xor(s, off, 64);
    __shared__ double sm[4];
    if ((threadIdx.x & 63) == 0) sm[threadIdx.x >> 6] = s;
    __syncthreads();
    const double tot = (sm[0] + sm[1]) + (sm[2] + sm[3]);
    const float meanf = (float)(tot / (double)((long long)M_DIM * K_DIM));
    const float s_w = 1.0f / fmaxf(meanf, 1e-5f);   // ref fp32 chain
    const float w_deq = 1.0f / s_w;

    // --- streaming ternary GEMV x8 ---
    const int wave = threadIdx.x >> 6;
    const int lane = threadIdx.x & 63;
    const int m0 = blockIdx.x * 16 + wave * 4;   // 4 W rows per wave

    const float* Wr0 = W + (size_t)(m0 + 0) * K_DIM;
    const float* Wr1 = W + (size_t)(m0 + 1) * K_DIM;
    const float* Wr2 = W + (size_t)(m0 + 2) * K_DIM;
    const float* Wr3 = W + (size_t)(m0 + 3) * K_DIM;

    float acc[4][8];
    #pragma unroll
    for (int r = 0; r < 4; ++r)
        #pragma unroll
        for (int n = 0; n < 8; ++n) acc[r][n] = 0.0f;

    #pragma unroll 2
    for (int k = lane * 4; k < K_DIM; k += 256) {
        float4 w0 = *(const float4*)(Wr0 + k);
        float4 w1 = *(const float4*)(Wr1 + k);
        float4 w2 = *(const float4*)(Wr2 + k);
        float4 w3 = *(const float4*)(Wr3 + k);
        float4 xv[8];
        #pragma unroll
        for (int n = 0; n < 8; ++n)
            xv[n] = *(const float4*)(xh + n * K_DIM + k);   // L2-resident

        float4 q0, q1, q2, q3;
        q0.x = quant1(w0.x, s_w); q0.y = quant1(w0.y, s_w);
        q0.z = quant1(w0.z, s_w); q0.w = quant1(w0.w, s_w);
        q1.x = quant1(w1.x, s_w); q1.y = quant1(w1.y, s_w);
        q1.z = quant1(w1.z, s_w); q1.w = quant1(w1.w, s_w);
        q2.x = quant1(w2.x, s_w); q2.y = quant1(w2.y, s_w);
        q2.z = quant1(w2.z, s_w); q2.w = quant1(w2.w, s_w);
        q3.x = quant1(w3.x, s_w); q3.y = quant1(w3.y, s_w);
        q3.z = quant1(w3.z, s_w); q3.w = quant1(w3.w, s_w);

        #pragma unroll
        for (int n = 0; n < 8; ++n) {
            acc[0][n] = fmaf(q0.x, xv[n].x, acc[0][n]);
            acc[0][n] = fmaf(q0.y, xv[n].y, acc[0][n]);
            acc[0][n] = fmaf(q0.z, xv[n].z, acc[0][n]);
            acc[0][n] = fmaf(q0.w, xv[n].w, acc[0][n]);
            acc[1][n] = fmaf(q1.x, xv[n].x, acc[1][n]);
            acc[1][n] = fmaf(q1.y, xv[n].y, acc[1][n]);
            acc[1][n] = fmaf(q1.z, xv[n].z, acc[1][n]);
            acc[1][n] = fmaf(q1.w, xv[n].w, acc[1][n]);
            acc[2][n] = fmaf(q2.x, xv[n].x, acc[2][n]);
            acc[2][n] = fmaf(q2.y, xv[n].y, acc[2][n]);
            acc[2][n] = fmaf(q2.z, xv[n].z, acc[2][n]);
            acc[2][n] = fmaf(q2.w, xv[n].w, acc[2][n]);
            acc[3][n] = fmaf(q3.x, xv[n].x, acc[3][n]);
            acc[3][n] = fmaf(q3.y, xv[n].y, acc[3][n]);
            acc[3][n] = fmaf(q3.z, xv[n].z, acc[3][n]);
            acc[3][n] = fmaf(q3.w, xv[n].w, acc[3][n]);
        }
    }

    // cross-lane reduction + store
    #pragma unroll
    for (int r = 0; r < 4; ++r) {
        #pragma unroll
        for (int n = 0; n < 8; ++n) {
            float v = acc[r][n];
            #pragma unroll
            for (int off = 32; off > 0; off >>= 1) v += __shfl_xor(v, off, 64);
            acc[r][n] = v;
        }
    }
    if (lane == 0) {
        #pragma unroll
        for (int r = 0; r < 4; ++r)
            #pragma unroll
            for (int n = 0; n < 8; ++n)
                out[n * M_DIM + (m0 + r)] = w_deq * acc[r][n];
    }
}

// ---------------------------------------------------------------------------
extern "C" void kernel_launch(void* const* d_in, const int* in_sizes, int n_in,
                              void* d_out, int out_size, void* d_ws, size_t ws_size,
                              hipStream_t stream) {
    const float* x = (const float*)d_in[0];   // [8, 8192] fp32
    const float* W = (const float*)d_in[1];   // [8192, 8192] fp32
    float* out = (float*)d_out;               // [8, 8192] fp32

    // ws layout: [0,16K) double partials[2048]; [32K, 32K+256K) x_hat
    double* partials = (double*)d_ws;
    float* xh = (float*)((char*)d_ws + 32768);

    k_pass1<<<RED_BLOCKS, 256, 0, stream>>>((const float4*)W, x, partials, xh);
    k_pass2<<<M_DIM / 16, 256, 0, stream>>>(W, xh, partials, out);
}